// Round 9
// baseline (229.067 us; speedup 1.0000x reference)
//
#include <hip/hip_runtime.h>
#include <math.h>

// Problem constants
#define NB 128     // batch
#define NC 128     // channels
#define NN 170     // nodes
#define NT 12      // length
#define NP 192     // padded node count (12 tiles of 16)
#define MP 176     // P row stride (halfs)

// Workspace regions (halfs)
#define EST_SZ ((size_t)NP * NC)            //   24,576 halfs (48 KB)
#define P_SZ   ((size_t)NB * NN * MP)       // 3,829,760 halfs (7.3 MB)

typedef _Float16 h8 __attribute__((ext_vector_type(8)));
typedef float    f4 __attribute__((ext_vector_type(4)));

// tanh via hw exp+rcp: ~6 VALU ops. rel err ~1e-6. Clamp sanitizes inf.
__device__ __forceinline__ float fast_tanh(float x) {
    float cx = fminf(fmaxf(x, -15.f), 15.f);
    float e  = __expf(2.f * cx);
    return (e - 1.f) * __builtin_amdgcn_rcpf(e + 1.f);
}

// ---------------------------------------------------------------------------
// KPREP: Est[m][c] = f16(Es[c][m]) for m<170, rows [170,192) zero (these
// zeros make EdL's pad cols exact zeros downstream). Proven.
// ---------------------------------------------------------------------------
__global__ __launch_bounds__(256) void kprep_est(const float* __restrict__ Es,
                                                 _Float16* __restrict__ Est) {
    int idx = blockIdx.x * 256 + threadIdx.x;       // [0, 192*128)
    int m = idx >> 7, c = idx & 127;
    Est[idx] = (m < NN) ? (_Float16)Es[c * NN + m] : (_Float16)0.f;
}

// ---------------------------------------------------------------------------
// KA — grid (2,128): block (h,b) = half h of batch b, 1024 thr = 16 waves.
// R7/R8 ledger: kA duration = per-block critical path; phase1 (the x[b]
// t-sum) was ~65us of it at only ~3.5 TB/s aggregate because every variant
// staged through LDS with barrier-phased rounds (16 barrier-synced rounds;
// R8's cross-barrier prefetch only covered ~1 HBM latency).
// THIS ROUND: phase1 is REGISTER-RESIDENT AND BARRIER-FREE. The t-sum is
// per-(n,c) independent: wave w, pass p own (ng,c) with p*16+w = ng+3*c;
// lane l -> n = ng*64+l. The 3 float4 loads/lane form a contiguous 3KB
// span per wave (48B/lane stride; L1 absorbs the triple line-touch; same
// TA instruction count as ideal coalescing). Sum in regs -> one
// ds_write_b16 to At[ATSW(n,c)]. 72 independent loads/thread, ZERO
// barriers, no Lb staging buffer (LDS drops to 122,880 B). The b16
// scatter's ~8-way bank conflict costs ~0.1us total (48KB) - irrelevant.
// GEMM1/GEMM2/softmax/P-write byte-identical to the R7/R8-proven code.
// All MFMA/swizzle patterns are the HW-verified family: A*B^T, operands
// k-contiguous h8 at quad*8; D: col=lane&15, row=quad*4+reg; XOR swizzle
// group' = group ^ (row&7) on 16B groups.
// ---------------------------------------------------------------------------
#define ATSW(row, c)  ((row) * 128 + (((((c) >> 3) ^ ((row) & 7)) << 3) | ((c) & 7)))
#define EDSW(row, m)  ((row) * 192 + (((((m) >> 3) ^ ((row) & 7)) << 3) | ((m) & 7)))
#define SCSTR 204

__global__ __launch_bounds__(1024) void kA_fused(const float* __restrict__ x,
                                                 const _Float16* __restrict__ Est,
                                                 _Float16* __restrict__ P) {
    const int h = blockIdx.x, b = blockIdx.y;
    const int r0 = h * 96;                          // this block's output rows
    const int t = threadIdx.x;                      // [0,1024)
    const int lane = t & 63, wave = t >> 6;         // wave [0,16)
    const int l15 = lane & 15, quad = lane >> 4;
    const int wr = wave >> 2, wc = wave & 3;        // 4x4 wave grid (GEMM1)

    __shared__ __align__(16) char     UN[192 * 128 * 2]; // 49,152 B At, later Sc
    __shared__ __align__(16) _Float16 EdL[192 * 192];    // 73,728 B
    _Float16* At = (_Float16*)UN;                   // [192 n][128 c] swizzled
    float*    Sc = (float*)UN;                      // [48][SCSTR] f32 (39,168 B)

    // ---- phase 1: barrier-free register t-sum -> At ----
    const float* __restrict__ xb = x + (size_t)b * NC * NN * NT;
    #pragma unroll
    for (int p = 0; p < 24; ++p) {
        int g3 = p * 16 + wave;                     // [0, 384) = 3 ng x 128 c
        int c  = g3 / 3;                            // const-div (magic mul)
        int ng = g3 - c * 3;
        int n  = ng * 64 + lane;                    // [0, 192)
        float sv = 0.f;
        if (n < NN) {
            const float4* q = reinterpret_cast<const float4*>(
                xb + ((size_t)c * NN + n) * NT);    // 48B, 16B-aligned
            float4 a0 = q[0], a1 = q[1], a2 = q[2];
            sv = ((a0.x + a0.y) + (a0.z + a0.w))
               + ((a1.x + a1.y) + (a1.z + a1.w))
               + ((a2.x + a2.y) + (a2.z + a2.w));
        }
        At[ATSW(n, c)] = (_Float16)sv;              // n>=170 rows exact 0
    }
    __syncthreads();                                // At complete (only barrier)

    // ---- GEMM1: EdL = tanh(At · Est^T), 16 waves, tile 48x48 each ----
    {
        f4 acc1[3][3] = {};
        #pragma unroll
        for (int kk = 0; kk < 4; ++kk) {            // K = 128
            int ks = kk * 32 + quad * 8;
            h8 a[3], bf[3];
            #pragma unroll
            for (int rt = 0; rt < 3; ++rt) {
                int row = wr * 48 + rt * 16 + l15;
                a[rt] = *reinterpret_cast<const h8*>(
                    &At[row * 128 + (((ks >> 3) ^ (row & 7)) << 3)]);
            }
            #pragma unroll
            for (int ci = 0; ci < 3; ++ci) {
                int m = wc * 48 + ci * 16 + l15;
                bf[ci] = *reinterpret_cast<const h8*>(Est + (size_t)m * NC + ks);
            }
            #pragma unroll
            for (int rt = 0; rt < 3; ++rt)
                #pragma unroll
                for (int ci = 0; ci < 3; ++ci)
                    acc1[rt][ci] = __builtin_amdgcn_mfma_f32_16x16x32_f16(
                        a[rt], bf[ci], acc1[rt][ci], 0, 0, 0);
        }
        // epilogue: tanh -> EdL (swizzled b16 writes)
        #pragma unroll
        for (int rt = 0; rt < 3; ++rt)
            #pragma unroll
            for (int ci = 0; ci < 3; ++ci) {
                int m = wc * 48 + ci * 16 + l15;
                #pragma unroll
                for (int reg = 0; reg < 4; ++reg) {
                    int n = wr * 48 + rt * 16 + quad * 4 + reg;
                    EdL[EDSW(n, m)] = (_Float16)fast_tanh(acc1[rt][ci][reg]);
                }
            }
    }
    __syncthreads();                                // EdL complete; At dead

    // ---- GEMM2: this half's 96 rows x 192 cols = 2x4 grid of 48x48 ----
    f4 acc2[3][3] = {};
    if (wave < 8) {
        const int gr = wave >> 2, gc = wave & 3;
        #pragma unroll 2
        for (int mc = 0; mc < 192; mc += 32) {      // K = 192 (pad cols are 0)
            int mg = (mc >> 3) + quad;
            h8 a2[3], b2[3];
            #pragma unroll
            for (int rt = 0; rt < 3; ++rt) {
                int row = r0 + gr * 48 + rt * 16 + l15;
                a2[rt] = *reinterpret_cast<const h8*>(
                    &EdL[row * 192 + ((mg ^ (row & 7)) << 3)]);
            }
            #pragma unroll
            for (int ci = 0; ci < 3; ++ci) {
                int row = gc * 48 + ci * 16 + l15;  // score col base
                b2[ci] = *reinterpret_cast<const h8*>(
                    &EdL[row * 192 + ((mg ^ (row & 7)) << 3)]);
            }
            #pragma unroll
            for (int rt = 0; rt < 3; ++rt)
                #pragma unroll
                for (int ci = 0; ci < 3; ++ci)
                    acc2[rt][ci] = __builtin_amdgcn_mfma_f32_16x16x32_f16(
                        a2[rt], b2[ci], acc2[rt][ci], 0, 0, 0);
        }
    }

    // ---- 2 rounds of 48 rows: scatter (waves gr==p) -> softmax (all) ----
    const float scale = 0.08838834764831845f;       // 1/sqrt(128)
    for (int p = 0; p < 2; ++p) {
        __syncthreads();                            // prev round's Sc reads done
        if (wave < 8 && (wave >> 2) == p) {
            const int gc = wave & 3;
            #pragma unroll
            for (int rt = 0; rt < 3; ++rt)
                #pragma unroll
                for (int ci = 0; ci < 3; ++ci) {
                    int col = gc * 48 + ci * 16 + l15;
                    #pragma unroll
                    for (int reg = 0; reg < 4; ++reg) {
                        int rloc = rt * 16 + quad * 4 + reg;
                        Sc[rloc * SCSTR + col] = fmaxf(acc2[rt][ci][reg] * scale, 0.f);
                    }
                }
        }
        __syncthreads();
        // proven wave-parallel softmax; wave owns 3 rows of this 48-row round
        #pragma unroll
        for (int rr = 0; rr < 3; ++rr) {
            int r = wave * 3 + rr;
            int n = r0 + p * 48 + r;
            if (n >= NN) continue;
            float v0 = Sc[r * SCSTR + lane];
            float v1 = Sc[r * SCSTR + lane + 64];
            int  k2i = lane + 128;
            bool has2 = (k2i < NN);
            float v2 = has2 ? Sc[r * SCSTR + k2i] : -1.f;
            float m = fmaxf(fmaxf(v0, v1), v2);
            #pragma unroll
            for (int off = 32; off; off >>= 1) m = fmaxf(m, __shfl_xor(m, off, 64));
            float e0 = __expf(v0 - m);
            float e1 = __expf(v1 - m);
            float e2 = has2 ? __expf(v2 - m) : 0.f;
            float s = e0 + e1 + e2;
            #pragma unroll
            for (int off = 32; off; off >>= 1) s += __shfl_xor(s, off, 64);
            float inv = 1.f / s;
            _Float16* Pr = P + ((size_t)(b * NN + n)) * MP;
            Pr[lane]      = (_Float16)(e0 * inv);
            Pr[lane + 64] = (_Float16)(e1 * inv);
            if (has2) Pr[k2i] = (_Float16)(e2 * inv);
        }
    }
}

// ---------------------------------------------------------------------------
// K4: mean over batch + threshold in one pass, 8-way accumulator ILP. Proven.
// ---------------------------------------------------------------------------
__global__ __launch_bounds__(256) void k4_mean_thresh(const _Float16* __restrict__ P,
                                                      float* __restrict__ out) {
    int p = blockIdx.x * 256 + threadIdx.x;
    if (p >= NN * NN) return;
    int n = p / NN, k = p - n * NN;
    const _Float16* base = P + (size_t)n * MP + k;
    float s0 = 0.f, s1 = 0.f, s2 = 0.f, s3 = 0.f;
    float s4 = 0.f, s5 = 0.f, s6 = 0.f, s7 = 0.f;
    #pragma unroll
    for (int b = 0; b < NB; b += 8) {
        s0 += (float)base[(size_t)(b + 0) * NN * MP];
        s1 += (float)base[(size_t)(b + 1) * NN * MP];
        s2 += (float)base[(size_t)(b + 2) * NN * MP];
        s3 += (float)base[(size_t)(b + 3) * NN * MP];
        s4 += (float)base[(size_t)(b + 4) * NN * MP];
        s5 += (float)base[(size_t)(b + 5) * NN * MP];
        s6 += (float)base[(size_t)(b + 6) * NN * MP];
        s7 += (float)base[(size_t)(b + 7) * NN * MP];
    }
    float s = ((s0 + s1) + (s2 + s3)) + ((s4 + s5) + (s6 + s7));
    out[p] = (s * (1.f / 128.f) > 0.5f) ? 1.f : 0.f;
}

// ---------------------------------------------------------------------------
// Workspace layout (halfs):
//   [0, EST_SZ)   : Est (f16, [192][128])   live through KA
//   [+, +P_SZ)    : P   (f16, [b][n][176])  dead after K4
// Total = 7.4 MB.
// ---------------------------------------------------------------------------
extern "C" void kernel_launch(void* const* d_in, const int* in_sizes, int n_in,
                              void* d_out, int out_size, void* d_ws, size_t ws_size,
                              hipStream_t stream) {
    const float* x  = (const float*)d_in[0];   // [128,128,170,12] f32
    const float* Es = (const float*)d_in[1];   // [128,170] f32
    float* out = (float*)d_out;                // [170,170] f32

    _Float16* Est = (_Float16*)d_ws;
    _Float16* P   = Est + EST_SZ;

    kprep_est<<<96, 256, 0, stream>>>(Es, Est);
    kA_fused<<<dim3(2, 128), 1024, 0, stream>>>(x, Est, P);
    k4_mean_thresh<<<113, 256, 0, stream>>>(P, out);
}